// Round 7
// baseline (104.306 us; speedup 1.0000x reference)
//
#include <hip/hip_runtime.h>
#include <math.h>

typedef _Float16 v8h __attribute__((ext_vector_type(8)));
typedef float    v4f __attribute__((ext_vector_type(4)));

// Tile: 4x4 pixels per 256-thread block (4 waves), 1024 blocks.
// Halo: 8x8 = 64 ref positions. LDS: logits 16x65 f32 + 16 self-logits = 4.2 KB.
// One barrier. QK via MFMA direct-from-global; PV via VALU direct-from-global (fp32).
// XCD swizzle: blockIdx % 8 = XCD (HW round-robin); each XCD gets a 16x2-tile
// vertical strip per batch -> halo rows shared within one XCD's L2.
__global__ __launch_bounds__(256, 6) void local_attn_hiocc(
    const float* __restrict__ main_,
    const float* __restrict__ main_value,
    const float* __restrict__ ref,
    const float* __restrict__ ref_value,
    float* __restrict__ out)
{
    __shared__ float Lf[16 * 65];   // [px][pos 0..63], stride 65 breaks 4-way banks
    __shared__ float SLf[16];       // self logits ||main_px||^2 (exact fp32)

    const int tid  = threadIdx.x;
    const int lane = tid & 63, w = tid >> 6;
    const int l15  = lane & 15, quad = lane >> 4;

    // strip swizzle: s = XCD, k = sequence within XCD
    const int s  = blockIdx.x & 7;
    const int k  = blockIdx.x >> 3;          // 0..127
    const int b  = k >> 5;                   // batch
    const int m  = k & 31;
    const int ty = m >> 1, tx = (s << 1) | (m & 1);
    const int h0 = ty << 2, w0 = tx << 2;

    // ===== phase A1: A-fragment (main) + self logit, straight from global =====
    v8h a[4];
    float sq = 0.f;
    {
        const float* ap = main_ +
            ((size_t)(((b << 6) + h0 + (l15 >> 2)) << 6) + (w0 + (l15 & 3))) * 128;
        #pragma unroll
        for (int ks = 0; ks < 4; ++ks) {
            const float4 v0 = *(const float4*)(ap + (ks << 5) + (quad << 3));
            const float4 v1 = *(const float4*)(ap + (ks << 5) + (quad << 3) + 4);
            const float a8[8] = {v0.x, v0.y, v0.z, v0.w, v1.x, v1.y, v1.z, v1.w};
            #pragma unroll
            for (int j = 0; j < 8; ++j) {
                a[ks][j] = (_Float16)a8[j];
                sq += a8[j] * a8[j];
            }
        }
    }

    // ===== phase A2: B-fragment (ref halo row) + QK MFMA =====
    {
        const int pos = (w << 4) + l15;              // 0..63 halo position
        const int hy = pos >> 3, hx = pos & 7;
        const int gh = h0 - 2 + hy, gw = w0 - 2 + hx;
        const bool ok = (gh >= 0) & (gh < 64) & (gw >= 0) & (gw < 64);
        const float* bp = ref +
            ((size_t)(((b << 6) + (ok ? gh : 0)) << 6) + (ok ? gw : 0)) * 128;
        v4f acc = {0, 0, 0, 0};
        #pragma unroll
        for (int ks = 0; ks < 4; ++ks) {
            float4 v0 = make_float4(0, 0, 0, 0), v1 = v0;
            if (ok) {
                v0 = *(const float4*)(bp + (ks << 5) + (quad << 3));
                v1 = *(const float4*)(bp + (ks << 5) + (quad << 3) + 4);
            }
            const float b8[8] = {v0.x, v0.y, v0.z, v0.w, v1.x, v1.y, v1.z, v1.w};
            v8h bh;
            #pragma unroll
            for (int j = 0; j < 8; ++j) bh[j] = (_Float16)b8[j];
            acc = __builtin_amdgcn_mfma_f32_16x16x32_f16(a[ks], bh, acc, 0, 0, 0);
        }
        // C layout: n(col)=l15 -> this wave's pos; m(row)=quad*4+j -> px
        #pragma unroll
        for (int j = 0; j < 4; ++j)
            Lf[((quad << 2) + j) * 65 + pos] = acc[j];   // OOB pos -> logit 0 (zero-pad)

        if (w == 0) {                                    // exact fp32 self logits
            sq += __shfl_xor(sq, 16);
            sq += __shfl_xor(sq, 32);
            if (quad == 0) SLf[l15] = sq;
        }
    }
    __syncthreads();

    // ===== phase B: softmax (26-way across lanes) + PV direct-from-global =====
    #pragma unroll
    for (int i = 0; i < 4; ++i) {
        const int t = (w << 2) + i;                     // tile pixel 0..15
        const int ty2 = t >> 2, tx2 = t & 3;
        const bool act = lane < 26;
        float lg = -INFINITY;
        if (lane < 25) {
            const int dy = lane / 5 - 2, dx = lane % 5 - 2;
            lg = Lf[t * 65 + ((ty2 + dy + 2) << 3) + (tx2 + dx + 2)];
        } else if (lane == 25) {
            lg = SLf[t];
        }
        float mx = lg;
        #pragma unroll
        for (int off = 32; off; off >>= 1) mx = fmaxf(mx, __shfl_xor(mx, off));
        const float e = act ? __expf(lg - mx) : 0.f;
        float sm = e;
        #pragma unroll
        for (int off = 32; off; off >>= 1) sm += __shfl_xor(sm, off);
        const float attn = e / sm;

        const int px = (((b << 6) + h0 + ty2) << 6) + (w0 + tx2);
        const float2 m2 = ((const float2*)(main_value + (size_t)px * 128))[lane];
        float2 o;
        const float a25 = __shfl(attn, 25);
        o.x = a25 * m2.x;
        o.y = a25 * m2.y;
        #pragma unroll
        for (int n = 0; n < 25; ++n) {
            const int gh = h0 + ty2 + n / 5 - 2, gw = w0 + tx2 + n % 5 - 2;
            if (gh >= 0 && gh < 64 && gw >= 0 && gw < 64) {   // wave-uniform
                const float2 v = ((const float2*)(ref_value +
                    (size_t)((((b << 6) + gh) << 6) + gw) * 128))[lane];
                const float an = __shfl(attn, n);
                o.x += an * v.x;
                o.y += an * v.y;
            }
        }
        ((float2*)(out + (size_t)px * 128))[lane] = o;
    }
}

extern "C" void kernel_launch(void* const* d_in, const int* in_sizes, int n_in,
                              void* d_out, int out_size, void* d_ws, size_t ws_size,
                              hipStream_t stream) {
    const float* main_      = (const float*)d_in[0];
    const float* main_value = (const float*)d_in[1];
    const float* ref        = (const float*)d_in[2];
    const float* ref_value  = (const float*)d_in[3];
    float* out = (float*)d_out;

    dim3 grid(1024), block(256);   // 4x4-px tiles, 6 blocks/CU (24 waves)
    local_attn_hiocc<<<grid, block, 0, stream>>>(main_, main_value, ref, ref_value, out);
}

// Round 8
// 103.104 us; speedup vs baseline: 1.0117x; 1.0117x over previous
//
#include <hip/hip_runtime.h>
#include <math.h>

typedef _Float16 v8h __attribute__((ext_vector_type(8)));
typedef float    v4f __attribute__((ext_vector_type(4)));

// ===================== kernel A: streaming L3 warm-up =====================
// Reads all four 8-MB inputs with coalesced grid-stride float4 sweeps so the
// cold HBM misses (after the harness's 268-MB poison fill evicts L2/L3) are
// serviced at streaming BW instead of latency-bound inside the compute kernel.
__global__ __launch_bounds__(256) void warm_l3(
    const float4* __restrict__ a, const float4* __restrict__ b,
    const float4* __restrict__ c, const float4* __restrict__ d)
{
    const int n4 = (4 * 64 * 64 * 128) / 4;          // 524288 float4 per array
    const int stride = gridDim.x * 256;
    float4 s = make_float4(0, 0, 0, 0);
    for (int i = blockIdx.x * 256 + threadIdx.x; i < n4; i += stride) {
        const float4 va = a[i], vb = b[i], vc = c[i], vd = d[i];
        s.x += va.x + vb.x + vc.x + vd.x;
        s.y += va.y + vb.y + vc.y + vd.y;
        s.z += va.z + vb.z + vc.z + vd.z;
        s.w += va.w + vb.w + vc.w + vd.w;
    }
    // sink to defeat DCE without touching memory
    __asm__ volatile("" :: "v"(s.x), "v"(s.y), "v"(s.z), "v"(s.w));
}

// ===================== kernel B: R6 structure (best known) =====================
// LDS (53,888 B):
//  VT [0, 32768):      128 ch x 128 pos fp16, 256 B rows, XOR-swizzled 16B chunks
//  L  [32768, 45568):  32 px x 100 fp32 logits
//  P  [45568, 53760):  32 px x 128 fp16, swizzled (zero except 26 cols/row)
//  SL [53760, 53888):  32 fp32 self-logits (||main_px||^2)
#define VT_OFF  0
#define L_OFF   32768
#define P_OFF   45568
#define SL_OFF  53760
#define LDS_SZ  53888

__device__ __forceinline__ int swz(int r, int c16) {
    return (r << 8) + ((c16 ^ (r & 15)) << 4);
}

__global__ __launch_bounds__(512, 4) void local_attn_direct(
    const float* __restrict__ main_,
    const float* __restrict__ main_value,
    const float* __restrict__ ref,
    const float* __restrict__ ref_value,
    float* __restrict__ out)
{
    __shared__ __align__(16) char S[LDS_SZ];

    const int tid = threadIdx.x;
    const int bid = blockIdx.x;
    const int b  = bid >> 7;
    const int h0 = ((bid >> 3) & 15) << 2;   // 4-row tile
    const int w0 = (bid & 7) << 3;           // 8-col tile
    const int lane = tid & 63, w = tid >> 6;
    const int l15 = lane & 15, quad = lane >> 4;
    const int mt = w >> 2, wl = w & 3;

    *(uint4*)(S + P_OFF + tid * 16) = make_uint4(0, 0, 0, 0);

    // ===== epoch 1a: VT staging (coalesced global -> LDS transpose) =====
    #pragma unroll
    for (int i = 0; i < 4; ++i) {
        const int tk = (w << 2) + i;
        const int pb = tk & 15;
        const int ch = ((tk >> 4) << 6) + lane;
        float pvv[8];
        #pragma unroll
        for (int j = 0; j < 8; ++j) {
            const int pos = (pb << 3) + j;
            float v = 0.f;
            if (pos < 96) {
                const int hy = pos / 12, hx = pos - hy * 12;
                const int gh = h0 - 2 + hy, gw = w0 - 2 + hx;
                if ((gh >= 0) & (gh < 64) & (gw >= 0) & (gw < 64))
                    v = ref_value[(size_t)((((b << 6) + gh) << 6) + gw) * 128 + ch];
            } else {
                const int t2 = pos - 96;
                v = main_value[(size_t)((((b << 6) + h0 + (t2 >> 3)) << 6) + (w0 + (t2 & 7))) * 128 + ch];
            }
            pvv[j] = v;
        }
        v8h hv;
        #pragma unroll
        for (int j = 0; j < 8; ++j) hv[j] = (_Float16)pvv[j];
        *(v8h*)(S + VT_OFF + swz(ch, pb)) = hv;
    }

    // ===== epoch 1b: QK straight from global =====
    v8h a[4];
    float sq = 0.f;
    {
        const int px = (mt << 4) + l15;
        const float* ap = main_ + (size_t)((((b << 6) + h0 + (px >> 3)) << 6) + (w0 + (px & 7))) * 128;
        #pragma unroll
        for (int ks = 0; ks < 4; ++ks) {
            const float4 v0 = *(const float4*)(ap + (ks << 5) + (quad << 3));
            const float4 v1 = *(const float4*)(ap + (ks << 5) + (quad << 3) + 4);
            const float a8[8] = {v0.x, v0.y, v0.z, v0.w, v1.x, v1.y, v1.z, v1.w};
            #pragma unroll
            for (int j = 0; j < 8; ++j) {
                a[ks][j] = (_Float16)a8[j];
                sq += a8[j] * a8[j];
            }
        }
        if (wl == 0) {
            sq += __shfl_xor(sq, 16);
            sq += __shfl_xor(sq, 32);
            if (quad == 0) *(float*)(S + SL_OFF + (px << 2)) = sq;
        }
    }
    #pragma unroll
    for (int nn = 0; nn < 2; ++nn) {
        const int nt = wl + (nn << 2);
        if (nt < 6) {
            const int hr = (nt << 4) + l15;
            const int hy = hr / 12, hx = hr - hy * 12;
            const int gh = h0 - 2 + hy, gw = w0 - 2 + hx;
            const bool ok = (gh >= 0) & (gh < 64) & (gw >= 0) & (gw < 64);
            const float* bp = ref + (size_t)((((b << 6) + (ok ? gh : 0)) << 6) + (ok ? gw : 0)) * 128;
            v4f acc = {0, 0, 0, 0};
            #pragma unroll
            for (int ks = 0; ks < 4; ++ks) {
                float4 v0 = make_float4(0, 0, 0, 0), v1 = v0;
                if (ok) {
                    v0 = *(const float4*)(bp + (ks << 5) + (quad << 3));
                    v1 = *(const float4*)(bp + (ks << 5) + (quad << 3) + 4);
                }
                const float b8[8] = {v0.x, v0.y, v0.z, v0.w, v1.x, v1.y, v1.z, v1.w};
                v8h bh;
                #pragma unroll
                for (int j = 0; j < 8; ++j) bh[j] = (_Float16)b8[j];
                acc = __builtin_amdgcn_mfma_f32_16x16x32_f16(a[ks], bh, acc, 0, 0, 0);
            }
            #pragma unroll
            for (int j = 0; j < 4; ++j) {
                const int px = (mt << 4) + (quad << 2) + j;
                *(float*)(S + L_OFF + px * 400 + (((nt << 4) + l15) << 2)) = acc[j];
            }
        }
    }
    __syncthreads();

    // ===== epoch 2: softmax -> P =====
    {
        const int half = lane >> 5, l = lane & 31;
        #pragma unroll
        for (int it = 0; it < 2; ++it) {
            const int t = (w << 2) + (it << 1) + half;
            const int ty = t >> 3, tx = t & 7;
            const bool act = l < 26;
            int col = 0;
            float lg = -INFINITY;
            if (l < 25) {
                const int dy = l / 5 - 2, dx = l % 5 - 2;
                col = (ty + dy + 2) * 12 + (tx + dx + 2);
                lg = *(const float*)(S + L_OFF + t * 400 + (col << 2));
            } else if (l == 25) {
                col = 96 + t;
                lg = *(const float*)(S + SL_OFF + (t << 2));
            }
            float m = lg;
            #pragma unroll
            for (int off = 16; off; off >>= 1) m = fmaxf(m, __shfl_xor(m, off));
            const float e = act ? __expf(lg - m) : 0.f;
            float s = e;
            #pragma unroll
            for (int off = 16; off; off >>= 1) s += __shfl_xor(s, off);
            if (act)
                *(_Float16*)(S + P_OFF + swz(t, col >> 3) + ((col & 7) << 1)) = (_Float16)(e / s);
        }
    }
    __syncthreads();

    // ===== epoch 3: O = P * VT via MFMA, store =====
    {
        const int ntp = wl << 1;
        const int prow = (mt << 4) + l15;
        const int v0r = (ntp << 4) + l15, v1r = v0r + 16;
        v4f acc0 = {0, 0, 0, 0}, acc1 = {0, 0, 0, 0};
        #pragma unroll
        for (int ks = 0; ks < 4; ++ks) {
            const int c16 = (ks << 2) + quad;
            const v8h pa  = *(const v8h*)(S + P_OFF  + swz(prow, c16));
            const v8h vt0 = *(const v8h*)(S + VT_OFF + swz(v0r,  c16));
            const v8h vt1 = *(const v8h*)(S + VT_OFF + swz(v1r,  c16));
            acc0 = __builtin_amdgcn_mfma_f32_16x16x32_f16(pa, vt0, acc0, 0, 0, 0);
            acc1 = __builtin_amdgcn_mfma_f32_16x16x32_f16(pa, vt1, acc1, 0, 0, 0);
        }
        #pragma unroll
        for (int j = 0; j < 4; ++j) {
            const int px = (mt << 4) + (quad << 2) + j;
            const size_t gbase =
                (size_t)((((b << 6) + h0 + (px >> 3)) << 6) + (w0 + (px & 7))) * 128;
            out[gbase + ((ntp    ) << 4) + l15] = acc0[j];
            out[gbase + ((ntp + 1) << 4) + l15] = acc1[j];
        }
    }
}

extern "C" void kernel_launch(void* const* d_in, const int* in_sizes, int n_in,
                              void* d_out, int out_size, void* d_ws, size_t ws_size,
                              hipStream_t stream) {
    const float* main_      = (const float*)d_in[0];
    const float* main_value = (const float*)d_in[1];
    const float* ref        = (const float*)d_in[2];
    const float* ref_value  = (const float*)d_in[3];
    float* out = (float*)d_out;

    // A: stream all inputs through L2/L3 at full BW (converts latency-bound
    //    cold misses in B into BW-bound streaming here)
    warm_l3<<<dim3(2048), dim3(256), 0, stream>>>(
        (const float4*)main_, (const float4*)main_value,
        (const float4*)ref,   (const float4*)ref_value);

    // B: compute with warm L3
    local_attn_direct<<<dim3(4 * 16 * 8), dim3(512), 0, stream>>>(
        main_, main_value, ref, ref_value, out);
}

// Round 9
// 101.161 us; speedup vs baseline: 1.0311x; 1.0192x over previous
//
#include <hip/hip_runtime.h>
#include <math.h>

typedef _Float16 v8h __attribute__((ext_vector_type(8)));
typedef float    v4f __attribute__((ext_vector_type(4)));

// LDS (21,760 B -> tiny; 2 blocks/CU co-resident, fast barriers):
//  L  [0, 12800):      32 px x 100 f32 logits (halo cols 0..95)
//  P  [12800, 20992):  32 px x 128 fp16, XOR-swizzled 16B chunks (zero except 26 cols)
//  SL [20992, 21120):  32 f32 self-logits (||main_px||^2)
//  RO [21120, 21632):  128 int: global row element-offset per position, -1 = OOB
#define L_OFF   0
#define P_OFF   12800
#define SL_OFF  20992
#define RO_OFF  21120
#define LDS_SZ  21760

__device__ __forceinline__ int swz(int r, int c16) {
    return (r << 8) + ((c16 ^ (r & 15)) << 4);
}

__global__ __launch_bounds__(512, 4) void local_attn_v3(
    const float* __restrict__ main_,
    const float* __restrict__ main_value,
    const float* __restrict__ ref,
    const float* __restrict__ ref_value,
    float* __restrict__ out)
{
    __shared__ __align__(16) char S[LDS_SZ];

    const int tid = threadIdx.x;
    const int bid = blockIdx.x;
    const int b  = bid >> 7;
    const int h0 = ((bid >> 3) & 15) << 2;   // 4-row tile
    const int w0 = (bid & 7) << 3;           // 8-col tile
    const int lane = tid & 63, w = tid >> 6;
    const int l15 = lane & 15, quad = lane >> 4;
    const int mt = w >> 2, wl = w & 3;

    // zero P (8 KB = 512 threads x 16 B)
    *(uint4*)(S + P_OFF + tid * 16) = make_uint4(0, 0, 0, 0);

    // precompute per-position global row offsets (element units), -1 = OOB
    if (tid < 128) {
        const int pos = tid;
        int off;
        if (pos < 96) {
            const int hy = pos / 12, hx = pos - hy * 12;
            const int gh = h0 - 2 + hy, gw = w0 - 2 + hx;
            const bool ok = (gh >= 0) & (gh < 64) & (gw >= 0) & (gw < 64);
            off = ok ? ((((b << 6) + gh) << 6) + gw) * 128 : -1;
        } else {
            const int t2 = pos - 96;
            off = ((((b << 6) + h0 + (t2 >> 3)) << 6) + (w0 + (t2 & 7))) * 128;
        }
        *(int*)(S + RO_OFF + (pos << 2)) = off;
    }

    // ===== phase 1: QK straight from global -> L, SL =====
    v8h a[4];
    float sq = 0.f;
    {
        const int px = (mt << 4) + l15;
        const float* ap = main_ + (size_t)((((b << 6) + h0 + (px >> 3)) << 6) + (w0 + (px & 7))) * 128;
        #pragma unroll
        for (int ks = 0; ks < 4; ++ks) {
            const float4 v0 = *(const float4*)(ap + (ks << 5) + (quad << 3));
            const float4 v1 = *(const float4*)(ap + (ks << 5) + (quad << 3) + 4);
            const float a8[8] = {v0.x, v0.y, v0.z, v0.w, v1.x, v1.y, v1.z, v1.w};
            #pragma unroll
            for (int j = 0; j < 8; ++j) {
                a[ks][j] = (_Float16)a8[j];
                sq += a8[j] * a8[j];
            }
        }
        if (wl == 0) {                       // exact fp32 self logits
            sq += __shfl_xor(sq, 16);
            sq += __shfl_xor(sq, 32);
            if (quad == 0) *(float*)(S + SL_OFF + (px << 2)) = sq;
        }
    }
    #pragma unroll
    for (int nn = 0; nn < 2; ++nn) {
        const int nt = wl + (nn << 2);
        if (nt < 6) {
            const int hr = (nt << 4) + l15;
            const int hy = hr / 12, hx = hr - hy * 12;
            const int gh = h0 - 2 + hy, gw = w0 - 2 + hx;
            const bool ok = (gh >= 0) & (gh < 64) & (gw >= 0) & (gw < 64);
            const float* bp = ref + (size_t)((((b << 6) + (ok ? gh : 0)) << 6) + (ok ? gw : 0)) * 128;
            v4f acc = {0, 0, 0, 0};
            #pragma unroll
            for (int ks = 0; ks < 4; ++ks) {
                float4 v0 = make_float4(0, 0, 0, 0), v1 = v0;
                if (ok) {
                    v0 = *(const float4*)(bp + (ks << 5) + (quad << 3));
                    v1 = *(const float4*)(bp + (ks << 5) + (quad << 3) + 4);
                }
                const float b8[8] = {v0.x, v0.y, v0.z, v0.w, v1.x, v1.y, v1.z, v1.w};
                v8h bh;
                #pragma unroll
                for (int j = 0; j < 8; ++j) bh[j] = (_Float16)b8[j];
                acc = __builtin_amdgcn_mfma_f32_16x16x32_f16(a[ks], bh, acc, 0, 0, 0);
            }
            // C layout: n(col)=l15 -> halo col, m(row)=quad*4+j -> px
            #pragma unroll
            for (int j = 0; j < 4; ++j) {
                const int px = (mt << 4) + (quad << 2) + j;
                *(float*)(S + L_OFF + px * 400 + (((nt << 4) + l15) << 2)) = acc[j];
            }
        }
    }
    __syncthreads();

    // ===== phase 2: softmax -> P (2 px per 32-lane half) =====
    {
        const int half = lane >> 5, l = lane & 31;
        #pragma unroll
        for (int it = 0; it < 2; ++it) {
            const int t = (w << 2) + (it << 1) + half;
            const int ty = t >> 3, tx = t & 7;
            const bool act = l < 26;
            int col = 0;
            float lg = -INFINITY;
            if (l < 25) {
                const int dy = l / 5 - 2, dx = l % 5 - 2;
                col = (ty + dy + 2) * 12 + (tx + dx + 2);
                lg = *(const float*)(S + L_OFF + t * 400 + (col << 2));   // OOB cols hold 0
            } else if (l == 25) {
                col = 96 + t;
                lg = *(const float*)(S + SL_OFF + (t << 2));
            }
            float m = lg;
            #pragma unroll
            for (int off = 16; off; off >>= 1) m = fmaxf(m, __shfl_xor(m, off));
            const float e = act ? __expf(lg - m) : 0.f;
            float s = e;
            #pragma unroll
            for (int off = 16; off; off >>= 1) s += __shfl_xor(s, off);
            if (act)
                *(_Float16*)(S + P_OFF + swz(t, col >> 3) + ((col & 7) << 1)) = (_Float16)(e / s);
        }
    }
    __syncthreads();

    // ===== phase 3: O = P (LDS) x V (global transpose-read) via MFMA =====
    {
        const int ntp  = wl << 1;
        const int ch0  = (ntp << 4) + l15;       // acc0 channels
        const int ch1  = ch0 + 16;               // acc1 channels
        const int prow = (mt << 4) + l15;
        v4f acc0 = {0, 0, 0, 0}, acc1 = {0, 0, 0, 0};
        #pragma unroll
        for (int ks = 0; ks < 4; ++ks) {
            const v8h pa = *(const v8h*)(S + P_OFF + swz(prow, (ks << 2) + quad));
            v8h b0, b1;
            const int kp = (ks << 5) + (quad << 3);
            #pragma unroll
            for (int j = 0; j < 8; ++j) {
                const int pos = kp + j;
                const int off = *(const int*)(S + RO_OFF + (pos << 2));
                const float* bp = (pos < 96) ? ref_value : main_value;
                // dense: lanes l15 -> 16 consecutive floats = one 64-B line
                const float va = (off >= 0) ? bp[off + ch0] : 0.f;
                const float vb = (off >= 0) ? bp[off + ch1] : 0.f;
                b0[j] = (_Float16)va;
                b1[j] = (_Float16)vb;
            }
            acc0 = __builtin_amdgcn_mfma_f32_16x16x32_f16(pa, b0, acc0, 0, 0, 0);
            acc1 = __builtin_amdgcn_mfma_f32_16x16x32_f16(pa, b1, acc1, 0, 0, 0);
        }
        #pragma unroll
        for (int j = 0; j < 4; ++j) {
            const int px = (mt << 4) + (quad << 2) + j;
            const size_t gbase =
                (size_t)((((b << 6) + h0 + (px >> 3)) << 6) + (w0 + (px & 7))) * 128;
            out[gbase + ch0] = acc0[j];
            out[gbase + ch1] = acc1[j];
        }
    }
}

extern "C" void kernel_launch(void* const* d_in, const int* in_sizes, int n_in,
                              void* d_out, int out_size, void* d_ws, size_t ws_size,
                              hipStream_t stream) {
    const float* main_      = (const float*)d_in[0];
    const float* main_value = (const float*)d_in[1];
    const float* ref        = (const float*)d_in[2];
    const float* ref_value  = (const float*)d_in[3];
    float* out = (float*)d_out;

    dim3 grid(4 * 16 * 8), block(512);   // 512 blocks (4x8 px tiles), 2 blocks/CU
    local_attn_v3<<<grid, block, 0, stream>>>(main_, main_value, ref, ref_value, out);
}